// Round 10
// baseline (61.033 us; speedup 1.0000x reference)
//
#include <hip/hip_runtime.h>
#include <stdint.h>

typedef __bf16 bf16_t;
typedef __bf16 bf16x8 __attribute__((ext_vector_type(8)));
typedef float  f32x4  __attribute__((ext_vector_type(4)));
typedef float  f32x16 __attribute__((ext_vector_type(16)));

// ws layout
#define WF_OFF    0u
#define SPL_OFF   1048576u                  // 64*8 planes * 4356 cells * 16B = 35,684,352
#define SILT_OFF  (1048576u + 35684352u)    // 8*4356*64*2B = 4,460,544

#define ABUF 4096
#define LDS_TOTAL 49152                     // max(3*ABUF, reduce 48K + pad)

// async global->LDS, 16B/lane; LDS dest = wave-uniform base + lane*16
__device__ __forceinline__ void gld_lds16(const void* g, void* l) {
  __builtin_amdgcn_global_load_lds(
      (const __attribute__((address_space(1))) uint32_t*)g,
      (__attribute__((address_space(3))) uint32_t*)(uintptr_t)l,
      16, 0, 0);
}

// ---------------- weight repack into step-major layout (verified R6-R9) ----------------
// Wf2[s][o][kk], s=0..323, o=0..63, kk=kh*8+j (16 bf16 per (s,o))
// spline steps s = q*9 + tap (q=0..31 channel-pair): c = q*2+kh, f = c*9+tap
// silu steps   s = 288 + cq*9 + tap (cq=0..3): c = cq*16+kk, f = c*9+tap
__global__ __launch_bounds__(256) void prep_w_kernel(
    const float* __restrict__ bw, const float* __restrict__ sw,
    const float* __restrict__ ss, bf16_t* __restrict__ Wf2) {
  int idx = blockIdx.x * 256 + threadIdx.x;   // < 324*64*16 = 331776
  int kk = idx & 15, o = (idx >> 4) & 63, s = idx >> 10;
  int kh = kk >> 3, j = kk & 7;
  float v;
  if (s < 288) {
    int q = s / 9, tap = s - q * 9;
    int c = q * 2 + kh;
    int f = c * 9 + tap;
    v = sw[(o * 576 + f) * 8 + j] * ss[o * 576 + f];
  } else {
    int t2 = s - 288;
    int cq = t2 / 9, tap = t2 - cq * 9;
    int c = cq * 16 + kk;
    int f = c * 9 + tap;
    v = bw[o * 576 + f];
  }
  Wf2[idx] = (bf16_t)v;
}

// ---------------- per-pixel precompute into PADDED layouts (verified) ----------------
__global__ __launch_bounds__(256) void precomp_kernel(
    const float* __restrict__ X, uint4* __restrict__ spl8,
    bf16_t* __restrict__ silT) {
  __shared__ bf16_t trans[64 * 72];
  const int t = threadIdx.x;
  const int bb = blockIdx.x;          // 512: (bimg, ih)
  const int bimg = bb >> 6, ih = bb & 63;
  const int iw = t & 63;
  const int c4 = t >> 6;

  const float* Xp = X + (((size_t)bimg * 64) << 12) + (ih << 6);

  const float G0 = -2.2f, G1 = 2.2f, INVH = 2.5f;

  for (int q = 0; q < 16; ++q) {
    int c = c4 * 16 + q;
    float x = Xp[((size_t)c << 12) + iw];

    float sl = x / (1.0f + __expf(-x));

    float tt = (x - G0) * INVH;
    int i0 = (int)tt;
    i0 = i0 < 0 ? 0 : (i0 > 10 ? 10 : i0);
    float u  = tt - (float)i0;
    float um = 1.0f - u;
    float u2 = u * u, u3 = u2 * u;
    float w0 = um * um * um * (1.0f / 6.0f);
    float w1 = (3.0f * u3 - 6.0f * u2 + 4.0f) * (1.0f / 6.0f);
    float w2 = (-3.0f * u3 + 3.0f * u2 + 3.0f * u + 1.0f) * (1.0f / 6.0f);
    float w3 = u3 * (1.0f / 6.0f);
    bool inr = (x >= G0) & (x < G1);

    union { bf16_t hh4[4]; unsigned long long u64; } pk;
    pk.hh4[0] = (bf16_t)w0; pk.hh4[1] = (bf16_t)w1;
    pk.hh4[2] = (bf16_t)w2; pk.hh4[3] = (bf16_t)w3;
    unsigned long long a = inr ? pk.u64 : 0ull;

    int sh = (i0 - 3) * 16;
    unsigned long long lo, hi;
    if (sh >= 0) {
      lo = (sh < 64) ? (a << (sh & 63)) : 0ull;
      hi = (sh == 0) ? 0ull
           : ((sh < 64) ? (a >> ((64 - sh) & 63)) : (a << ((sh - 64) & 63)));
    } else {
      lo = a >> ((-sh) & 63);
      hi = 0ull;
    }
    uint4 wv;
    wv.x = (unsigned)(lo & 0xffffffffull); wv.y = (unsigned)(lo >> 32);
    wv.z = (unsigned)(hi & 0xffffffffull); wv.w = (unsigned)(hi >> 32);
    spl8[(size_t)(bimg * 64 + c) * 4356 + (ih + 1) * 66 + (iw + 1)] = wv;

    trans[iw * 72 + c] = (bf16_t)sl;
  }
  __syncthreads();
  #pragma unroll
  for (int p = 0; p < 2; ++p) {
    int iw2 = (t >> 3) + p * 32;
    int c8  = (t & 7) * 8;
    bf16x8 v = *(const bf16x8*)&trans[iw2 * 72 + c8];
    *(bf16x8*)&silT[((size_t)(bimg * 4356 + (ih + 1) * 66 + (iw2 + 1)) << 6) + c8] = v;
  }
}

// ---------------- border fill: x=0 window / silu 0 (grid-stride, 260 cells) ----------------
__global__ __launch_bounds__(256) void fill_border_kernel(
    uint4* __restrict__ spl8, bf16_t* __restrict__ silT) {
  const int b = blockIdx.x;   // 0..511: spl8 plane ; 512..519: silT image
  for (int s = threadIdx.x; s < 260; s += 256) {
    int ihp, iwp;
    if (s < 66)       { ihp = 0;        iwp = s; }
    else if (s < 132) { ihp = 65;       iwp = s - 66; }
    else if (s < 196) { ihp = s - 131;  iwp = 0; }    // 1..64
    else              { ihp = s - 195;  iwp = 65; }   // 1..64
    if (b < 512) {
      uint4 cw; cw.x = 0u; cw.y = 0x3EF53CABu; cw.z = 0x3CAB3EF5u; cw.w = 0u;
      spl8[(size_t)b * 4356 + ihp * 66 + iwp] = cw;
    } else {
      int img = b - 512;
      uint4 z; z.x = z.y = z.z = z.w = 0u;
      size_t base = ((size_t)(img * 4356 + ihp * 66 + iwp) << 6);
      #pragma unroll
      for (int j = 0; j < 8; ++j)
        *(uint4*)&silT[base + j * 8] = z;
    }
  }
}

// ---------------- main fused GEMM ----------------
// block = 64 px (8x8) x 64 och; 4 waves, K split by taps {0,1}{2,3}{4,5}{6,7,8}.
// A: LDS triple-buffer via DMA (1 instr/wave/chunk). B: register triple-buffer
// direct from L2 (coalesced 1KB/wave loads), issued 2 chunks ahead.
__global__ __launch_bounds__(256, 2) void convkan_kernel(
    const uint4* __restrict__ spl8, const bf16_t* __restrict__ silT,
    const bf16_t* __restrict__ Wf2, float* __restrict__ out) {
  extern __shared__ char smraw[];
  char* const a0 = smraw;
  char* const a1 = smraw + ABUF;
  char* const a2 = smraw + 2 * ABUF;

  const int t    = threadIdx.x;
  const int lane = t & 63;
  const int w    = t >> 6;        // wave 0..3 (tap group)
  const int r    = lane & 31;     // A-row(px) / B-col(och)
  const int kh   = lane >> 5;     // k-half within K=16

  const int b   = blockIdx.x;
  const int rb  = ((b & 7) << 6) | (b >> 3);   // XCD-chunked (512%8==0, bijective)
  const int img = rb >> 6;
  const int rem = rb & 63;
  const int ohb = rem >> 3, owb = rem & 7;
  const int arow0 = (ohb * 8) * 66 + owb * 8;  // padded cell of block origin

  // ---- A staging geometry: slot = t; h = t>>7; 10x12 grid (120 valid) ----
  const int h = t >> 7;
  int idx = t & 127;
  int row = idx / 12, col = idx - row * 12;
  if (idx >= 120 || col >= 10) { row = 0; col = 0; }
  const int cellOff = arow0 + row * 66 + col;
  const size_t splOffH = (size_t)(img * 64 + h) * 4356 + cellOff;          // + cs*8712
  const size_t silOffH = (((size_t)(img * 4356 + cellOff)) << 6) + h * 8;  // + (cs-32)*16

  // ---- compute-read geometry ----
  const int khq = kh * 128;                    // A slot base for this k-half
  const int pb0 = (r >> 3) * 12 + (r & 7);     // px 0..31 cell
  const int pb1 = pb0 + 48;                    // px 32..63 (+4 rows)

  const int tap0 = (w < 3) ? (w * 2) : 6;
  const int ntap = (w < 3) ? 2 : 3;

  f32x16 acc[2][2];
  #pragma unroll
  for (int a = 0; a < 2; ++a)
    #pragma unroll
    for (int c = 0; c < 2; ++c) acc[a][c] = (f32x16)0.0f;

  bf16x8 Bx[3][2], By[3][2], Bz[3][2];
  const bf16_t* const BW = Wf2 + r * 16 + kh * 8;

#define SBASE(cs) ((cs) < 32 ? (cs) * 9 : 288 + ((cs) - 32) * 9)

#define STAGEA(cs, abuf) do {                                                   \
    if ((cs) < 32) gld_lds16(spl8 + splOffH + (size_t)(cs) * 8712,              \
                             (abuf) + (w << 10));                               \
    else           gld_lds16(silT + silOffH + (size_t)((cs) - 32) * 16,         \
                             (abuf) + (w << 10));                               \
  } while (0)

#define ISSUEB(cs, BB) do {                                                     \
    const int sb_ = SBASE(cs);                                                  \
    _Pragma("unroll")                                                           \
    for (int tt = 0; tt < 3; ++tt) if (tt < ntap) {                             \
      const bf16_t* bp_ = BW + (size_t)(sb_ + tap0 + tt) * 1024;                \
      BB[tt][0] = *(const bf16x8*)bp_;                                          \
      BB[tt][1] = *(const bf16x8*)(bp_ + 512);                                  \
    }                                                                           \
  } while (0)

#define COMPUTE(AUSE, BB) do {                                                  \
    _Pragma("unroll")                                                           \
    for (int tt = 0; tt < 3; ++tt) if (tt < ntap) {                             \
      const int tap_  = tap0 + tt;                                              \
      const int ki_   = (tap_ * 11) >> 5;                                       \
      const int koff_ = ki_ * 12 + (tap_ - 3 * ki_);                            \
      bf16x8 A0_ = *(const bf16x8*)((AUSE) + ((khq + pb0 + koff_) << 4));       \
      bf16x8 A1_ = *(const bf16x8*)((AUSE) + ((khq + pb1 + koff_) << 4));       \
      acc[0][0] = __builtin_amdgcn_mfma_f32_32x32x16_bf16(A0_, BB[tt][0], acc[0][0], 0, 0, 0); \
      acc[0][1] = __builtin_amdgcn_mfma_f32_32x32x16_bf16(A0_, BB[tt][1], acc[0][1], 0, 0, 0); \
      acc[1][0] = __builtin_amdgcn_mfma_f32_32x32x16_bf16(A1_, BB[tt][0], acc[1][0], 0, 0, 0); \
      acc[1][1] = __builtin_amdgcn_mfma_f32_32x32x16_bf16(A1_, BB[tt][1], acc[1][1], 0, 0, 0); \
    }                                                                           \
  } while (0)

#define BODY(CI, AUSE, AISS, BUSE, BISS, VM) do {                               \
    asm volatile("s_waitcnt vmcnt(" #VM ")" ::: "memory");                      \
    __builtin_amdgcn_s_barrier();                                               \
    __builtin_amdgcn_sched_barrier(0);                                          \
    if ((CI) + 2 < 36) { STAGEA((CI) + 2, AISS); ISSUEB((CI) + 2, BISS); }      \
    COMPUTE(AUSE, BUSE);                                                        \
  } while (0)

  // prologue: two regions (fenced so vmcnt region-counting holds)
  STAGEA(0, a0); ISSUEB(0, Bx);
  asm volatile("" ::: "memory");
  STAGEA(1, a1); ISSUEB(1, By);

  for (int i = 0; i < 11; ++i) {
    const int c3 = i * 3;
    BODY(c3 + 0, a0, a2, Bx, Bz, 5);
    BODY(c3 + 1, a1, a0, By, Bx, 5);
    BODY(c3 + 2, a2, a1, Bz, By, 5);
  }
  BODY(33, a0, a2, Bx, Bz, 5);   // issues A(35)->a2, B(35)->Bz
  BODY(34, a1, a0, By, Bx, 5);   // no new issues (ci+2=36)
  BODY(35, a2, a1, Bz, By, 0);   // final: full drain

  // ---- 4-way K-reduce: waves 1-3 dump, wave 0 combines + stores ----
  __syncthreads();
  float* red = (float*)smraw;
  if (w != 0) {
    #pragma unroll
    for (int pxt = 0; pxt < 2; ++pxt)
      #pragma unroll
      for (int ot = 0; ot < 2; ++ot)
        #pragma unroll
        for (int q = 0; q < 16; ++q)
          red[(((w - 1) * 64) + (pxt * 2 + ot) * 16 + q) * 64 + lane] = acc[pxt][ot][q];
  }
  __syncthreads();
  if (w == 0) {
    #pragma unroll
    for (int pxt = 0; pxt < 2; ++pxt) {
      #pragma unroll
      for (int ot = 0; ot < 2; ++ot) {
        const int o = ot * 32 + r;
        float* obase = out + (((size_t)(img * 64 + o)) << 12);
        #pragma unroll
        for (int g = 0; g < 4; ++g) {
          f32x4 v;
          #pragma unroll
          for (int iq = 0; iq < 4; ++iq) {
            int q = g * 4 + iq;
            int ri = (pxt * 2 + ot) * 16 + q;
            v[iq] = acc[pxt][ot][q]
                  + red[(0 * 64 + ri) * 64 + lane]
                  + red[(1 * 64 + ri) * 64 + lane]
                  + red[(2 * 64 + ri) * 64 + lane];
          }
          int px = pxt * 32 + 8 * g + 4 * kh;
          *(f32x4*)(obase + (ohb * 8 + (px >> 3)) * 64 + owb * 8 + (px & 7)) = v;
        }
      }
    }
  }
#undef BODY
#undef COMPUTE
#undef ISSUEB
#undef STAGEA
#undef SBASE
}

extern "C" void kernel_launch(void* const* d_in, const int* in_sizes, int n_in,
                              void* d_out, int out_size, void* d_ws, size_t ws_size,
                              hipStream_t stream) {
  const float* x  = (const float*)d_in[0];
  const float* bw = (const float*)d_in[1];
  const float* sw = (const float*)d_in[2];
  const float* ss = (const float*)d_in[3];

  char* ws = (char*)d_ws;
  bf16_t* Wf2  = (bf16_t*)(ws + WF_OFF);
  uint4*  spl8 = (uint4*)(ws + SPL_OFF);
  bf16_t* silT = (bf16_t*)(ws + SILT_OFF);
  float*  o    = (float*)d_out;

  prep_w_kernel<<<1296, 256, 0, stream>>>(bw, sw, ss, Wf2);
  precomp_kernel<<<512, 256, 0, stream>>>(x, spl8, silT);
  fill_border_kernel<<<520, 256, 0, stream>>>(spl8, silT);
  convkan_kernel<<<512, 256, LDS_TOTAL, stream>>>(spl8, silT, Wf2, o);
}

// Round 11
// 48.962 us; speedup vs baseline: 1.2465x; 1.2465x over previous
//
#include <hip/hip_runtime.h>
#include <stdint.h>

typedef __bf16 bf16_t;
typedef __bf16 bf16x8 __attribute__((ext_vector_type(8)));
typedef float  f32x4  __attribute__((ext_vector_type(4)));
typedef float  f32x16 __attribute__((ext_vector_type(16)));

// LDS layout (bytes): B0 [0,18432) B1 [18432,36864) A0 [36864,40960) A1 [40960,45056)
// epilogue reduce unions from 0 (needs 49152)
#define LDS_TOTAL 49152

// async global->LDS, 16B/lane; LDS dest = wave-uniform base + lane*16
__device__ __forceinline__ void gld_lds16(const void* g, void* l) {
  __builtin_amdgcn_global_load_lds(
      (const __attribute__((address_space(1))) uint32_t*)g,
      (__attribute__((address_space(3))) uint32_t*)(uintptr_t)l,
      16, 0, 0);
}

// ---------------- weight repack into step-major layout (verified R6-R10) ----------------
// Wf2[s][o][kk], s=0..323, o=0..63, kk=kh*8+j (16 bf16 per (s,o))
// spline steps s = q*9 + tap (q=0..31 channel-pair): c = q*2+kh, f = c*9+tap
// silu steps   s = 288 + cq*9 + tap (cq=0..3): c = cq*16+kk, f = c*9+tap
__global__ __launch_bounds__(256) void prep_w_kernel(
    const float* __restrict__ bw, const float* __restrict__ sw,
    const float* __restrict__ ss, bf16_t* __restrict__ Wf2) {
  int idx = blockIdx.x * 256 + threadIdx.x;   // < 324*64*16 = 331776
  int kk = idx & 15, o = (idx >> 4) & 63, s = idx >> 10;
  int kh = kk >> 3, j = kk & 7;
  float v;
  if (s < 288) {
    int q = s / 9, tap = s - q * 9;
    int c = q * 2 + kh;
    int f = c * 9 + tap;
    v = sw[(o * 576 + f) * 8 + j] * ss[o * 576 + f];
  } else {
    int t2 = s - 288;
    int cq = t2 / 9, tap = t2 - cq * 9;
    int c = cq * 16 + kk;
    int f = c * 9 + tap;
    v = bw[o * 576 + f];
  }
  Wf2[idx] = (bf16_t)v;
}

// ---------------- main fused kernel: window/silu computed in-kernel ----------------
// block = 64 px (8x8) x 64 och; 4 waves, K split by taps {0,1}{2,3}{4,5}{6,7,8}.
// A: built by VALU from raw X (x loaded 2 chunks ahead), double-buffered LDS.
// B: DMA-staged double buffer (R8-proven). Per-chunk __syncthreads.
__global__ __launch_bounds__(256, 2) void convkan_kernel(
    const float* __restrict__ X, const bf16_t* __restrict__ Wf2,
    float* __restrict__ out) {
  extern __shared__ char smraw[];
  char* const Bb0 = smraw;
  char* const Bb1 = smraw + 18432;
  char* const Ab0 = smraw + 36864;
  char* const Ab1 = smraw + 40960;

  const int t    = threadIdx.x;
  const int lane = t & 63;
  const int w    = t >> 6;        // wave 0..3 (tap group)
  const int r    = lane & 31;     // A-row(px) / B-col(och)
  const int kh   = lane >> 5;     // k-half within K=16

  const int b   = blockIdx.x;
  const int rb  = ((b & 7) << 6) | (b >> 3);   // XCD-chunked (512%8==0, bijective)
  const int img = rb >> 6;
  const int rem = rb & 63;
  const int ohb = rem >> 3, owb = rem & 7;

  // ---- A staging geometry: thread -> (channel-half h, halo cell) on 10x12 grid ----
  const int h   = t >> 7;
  const int idx = t & 127;
  const int row = idx / 12, col = idx - row * 12;
  const bool valid = (idx < 120) && (col < 10);
  const int ih = ohb * 8 + row - 1;
  const int iw = owb * 8 + col - 1;
  const bool inb = valid && ((unsigned)ih < 64u) && ((unsigned)iw < 64u);
  const float* Ximg = X + (((size_t)img * 64) << 12);
  const int pixoff = (ih << 6) + iw;

  // ---- compute-read geometry (verified R9/R10 12-wide conventions) ----
  const int khq = kh * 128;
  const int pb0 = (r >> 3) * 12 + (r & 7);
  const int pb1 = pb0 + 48;
  const int tap0 = (w < 3) ? (w * 2) : 6;
  const int ntap = (w < 3) ? 2 : 3;

  const float G0 = -2.2f, G1 = 2.2f, INVH = 2.5f;

  f32x16 acc[2][2];
  #pragma unroll
  for (int a = 0; a < 2; ++a)
    #pragma unroll
    for (int c = 0; c < 2; ++c) acc[a][c] = (f32x16)0.0f;

  auto XLOAD = [&](int cs, float* xr) {
    if (cs < 32) {
      xr[0] = inb ? Ximg[(((size_t)(2 * cs + h)) << 12) + pixoff] : 0.0f;
    } else {
      const int c0 = (cs - 32) * 16 + h * 8;
      #pragma unroll
      for (int j = 0; j < 8; ++j)
        xr[j] = inb ? Ximg[(((size_t)(c0 + j)) << 12) + pixoff] : 0.0f;
    }
  };

  auto WINW = [&](int cs, const float* xr, char* abuf) {
    if (cs < 32) {
      // uniform cubic B-spline window (verified R1-R10)
      float x  = xr[0];
      float tt = (x - G0) * INVH;
      int  i0  = (int)tt;
      i0 = i0 < 0 ? 0 : (i0 > 10 ? 10 : i0);
      float u  = tt - (float)i0;
      float um = 1.0f - u;
      float u2 = u * u, u3 = u2 * u;
      float w0 = um * um * um * (1.0f / 6.0f);
      float w1 = (3.0f * u3 - 6.0f * u2 + 4.0f) * (1.0f / 6.0f);
      float w2 = (-3.0f * u3 + 3.0f * u2 + 3.0f * u + 1.0f) * (1.0f / 6.0f);
      float w3 = u3 * (1.0f / 6.0f);
      bool inr = (x >= G0) & (x < G1);

      union { bf16_t hh4[4]; unsigned long long u64; } pk;
      pk.hh4[0] = (bf16_t)w0; pk.hh4[1] = (bf16_t)w1;
      pk.hh4[2] = (bf16_t)w2; pk.hh4[3] = (bf16_t)w3;
      unsigned long long a = inr ? pk.u64 : 0ull;

      int sh = (i0 - 3) * 16;
      unsigned long long lo, hi;
      if (sh >= 0) {
        lo = (sh < 64) ? (a << (sh & 63)) : 0ull;
        hi = (sh == 0) ? 0ull
             : ((sh < 64) ? (a >> ((64 - sh) & 63)) : (a << ((sh - 64) & 63)));
      } else {
        lo = a >> ((-sh) & 63);
        hi = 0ull;
      }
      uint4 wv;
      wv.x = (unsigned)(lo & 0xffffffffull); wv.y = (unsigned)(lo >> 32);
      wv.z = (unsigned)(hi & 0xffffffffull); wv.w = (unsigned)(hi >> 32);
      if (valid) *(uint4*)(abuf + ((h * 128 + idx) << 4)) = wv;
    } else {
      union { bf16_t hh8[8]; bf16x8 v; } pk;
      #pragma unroll
      for (int j = 0; j < 8; ++j) {
        float x = xr[j];
        pk.hh8[j] = (bf16_t)(x / (1.0f + __expf(-x)));
      }
      if (valid) *(bf16x8*)(abuf + ((2 * idx + h) << 4)) = pk.v;
    }
  };

  auto STAGEB = [&](int cs, char* bufB) {
    const bf16_t* bsrc = Wf2 + (size_t)(cs < 32 ? cs * 9 : 288 + (cs - 32) * 9) * 1024;
    #pragma unroll
    for (int u = 0; u < 4; ++u)
      gld_lds16(bsrc + ((u * 256 + t) << 3), bufB + ((u * 256 + (w << 6)) << 4));
    if (t < 128)
      gld_lds16(bsrc + ((1024 + t) << 3), bufB + ((1024 + (w << 6)) << 4));
  };

  auto COMPUTE = [&](int ci, const char* bufA, const char* bufB) {
    const bool spline = (ci < 32);
    #pragma unroll
    for (int tt = 0; tt < 3; ++tt) if (tt < ntap) {
      const int tap  = tap0 + tt;
      const int ki   = (tap * 11) >> 5;
      const int koff = ki * 12 + (tap - 3 * ki);
      const int c0 = pb0 + koff, c1 = pb1 + koff;
      const int au0 = spline ? (khq + c0) : (2 * c0 + kh);
      const int au1 = spline ? (khq + c1) : (2 * c1 + kh);
      bf16x8 A0f = *(const bf16x8*)(bufA + (au0 << 4));
      bf16x8 A1f = *(const bf16x8*)(bufA + (au1 << 4));
      const char* bt = bufB + (tap << 11) + r * 32 + kh * 16;
      bf16x8 B0f = *(const bf16x8*)bt;
      bf16x8 B1f = *(const bf16x8*)(bt + 1024);
      acc[0][0] = __builtin_amdgcn_mfma_f32_32x32x16_bf16(A0f, B0f, acc[0][0], 0, 0, 0);
      acc[0][1] = __builtin_amdgcn_mfma_f32_32x32x16_bf16(A0f, B1f, acc[0][1], 0, 0, 0);
      acc[1][0] = __builtin_amdgcn_mfma_f32_32x32x16_bf16(A1f, B0f, acc[1][0], 0, 0, 0);
      acc[1][1] = __builtin_amdgcn_mfma_f32_32x32x16_bf16(A1f, B1f, acc[1][1], 0, 0, 0);
    }
  };

  // ---- prologue ----
  float xP[8], xQ[8];
  XLOAD(0, xP);
  WINW(0, xP, Ab0);          // one-time stall on x(0)
  XLOAD(1, xP);              // xP now holds x(1)
  STAGEB(0, Bb0);
  __syncthreads();

  // ---- main loop: pair-unrolled so xP/xQ roles are static ----
  for (int i = 0; i < 18; ++i) {
    {
      const int ci = 2 * i;                 // even: uses A0/B0
      if (ci + 2 < 36) XLOAD(ci + 2, xQ);
      if (ci + 1 < 36) { STAGEB(ci + 1, Bb1); WINW(ci + 1, xP, Ab1); }
      COMPUTE(ci, Ab0, Bb0);
      __syncthreads();
    }
    {
      const int ci = 2 * i + 1;             // odd: uses A1/B1
      if (ci + 2 < 36) XLOAD(ci + 2, xP);
      if (ci + 1 < 36) { STAGEB(ci + 1, Bb0); WINW(ci + 1, xQ, Ab0); }
      COMPUTE(ci, Ab1, Bb1);
      __syncthreads();
    }
  }

  // ---- 4-way K-reduce: waves 1-3 dump, wave 0 combines + stores (R8 verbatim) ----
  float* red = (float*)smraw;
  if (w != 0) {
    #pragma unroll
    for (int pxt = 0; pxt < 2; ++pxt)
      #pragma unroll
      for (int ot = 0; ot < 2; ++ot)
        #pragma unroll
        for (int q = 0; q < 16; ++q)
          red[(((w - 1) * 64) + (pxt * 2 + ot) * 16 + q) * 64 + lane] = acc[pxt][ot][q];
  }
  __syncthreads();
  if (w == 0) {
    #pragma unroll
    for (int pxt = 0; pxt < 2; ++pxt) {
      #pragma unroll
      for (int ot = 0; ot < 2; ++ot) {
        const int o = ot * 32 + r;
        float* obase = out + (((size_t)(img * 64 + o)) << 12);
        #pragma unroll
        for (int g = 0; g < 4; ++g) {
          f32x4 v;
          #pragma unroll
          for (int iq = 0; iq < 4; ++iq) {
            int q = g * 4 + iq;
            int ri = (pxt * 2 + ot) * 16 + q;
            v[iq] = acc[pxt][ot][q]
                  + red[(0 * 64 + ri) * 64 + lane]
                  + red[(1 * 64 + ri) * 64 + lane]
                  + red[(2 * 64 + ri) * 64 + lane];
          }
          int px = pxt * 32 + 8 * g + 4 * kh;
          *(f32x4*)(obase + (ohb * 8 + (px >> 3)) * 64 + owb * 8 + (px & 7)) = v;
        }
      }
    }
  }
}

extern "C" void kernel_launch(void* const* d_in, const int* in_sizes, int n_in,
                              void* d_out, int out_size, void* d_ws, size_t ws_size,
                              hipStream_t stream) {
  const float* x  = (const float*)d_in[0];
  const float* bw = (const float*)d_in[1];
  const float* sw = (const float*)d_in[2];
  const float* ss = (const float*)d_in[3];

  bf16_t* Wf2 = (bf16_t*)d_ws;        // 324*64*16*2 = 663,552 B
  float*  o   = (float*)d_out;

  prep_w_kernel<<<1296, 256, 0, stream>>>(bw, sw, ss, Wf2);
  convkan_kernel<<<512, 256, LDS_TOTAL, stream>>>(x, Wf2, o);
}